// Round 15
// baseline (14.559 us; speedup 1.0000x reference)
//
#include <hip/hip_runtime.h>

#define GB 64
#define GN 128
#define F_OBS 64
#define F_TOT 80
#define ISPLIT 32
#define IPB (GN / ISPLIT)   // 4 i-rows per block

typedef __attribute__((ext_vector_type(16))) float f32x16;

// R14 (best: 14.5us) + ONE change: row/w streaming via s_load_dwordx16.
// R13 calibration showed t_hot ~2x its 1.7us VALU floor at VALUBusy 55%;
// the hot loop issues 80 SMEM ops/wave-pass (64 row dwordx4 + 16 w) vs 512
// VALU -- scalar-pipe issue slots + lgkmcnt wait chains are the suspected
// co-limiter (R10 batch-issue neutral, R12 LDS worse => op COUNT, not
// ordering). f32x16 uniform loads cut SMEM ops 4x (80 -> 20). Row base is
// 64B-aligned (stride 320B, offsets multiples of 1280B). Per-acc k-order
// unchanged (ascending) -> bitwise-identical outputs.
//
// Standing lessons: two plain dispatches beat merged variants (R5/R7/R11);
// no cross-block ordering (R2); no atomics/memset (R5); rows uniform on the
// scalar pipe, never per-lane gathers (R7: 8x HBM); ISPLIT=32 / 4 waves/SIMD
// occupancy sweet spot (R8/R9); XCD-clustered batches keep h L2-resident
// (R13/R14: FETCH 2.5MB->L2 hits, -1.4us).
__global__ __launch_bounds__(128, 4) void glcn_main(
    const float* __restrict__ h, const float* __restrict__ w,
    float* __restrict__ Aout, float* __restrict__ part) {
  const int blk = blockIdx.x;
  const int b  = (blk & 7) + 8 * ((blk >> 3) & 7);   // batch: XCD-clustered
  const int q  = blk >> 6;                           // i-split 0..31
  const int is = q * IPB;                            // block-uniform
  const int j  = threadIdx.x;                        // 0..127

  const float* rowj = h + ((size_t)(b * GN + j)) * F_TOT;    // per-lane
  const float* rows = h + ((size_t)(b * GN + is)) * F_TOT;   // uniform

  // Own row prefetched once: 16 independent float4 loads, one drain.
  float4 hj[F_OBS / 4];
#pragma unroll
  for (int kq = 0; kq < F_OBS / 4; ++kq)
    hj[kq] = *reinterpret_cast<const float4*>(rowj + 4 * kq);

  // Whole w in 4 scalar dwordx16 loads (reused by all 4 rows).
  const f32x16* w16 = reinterpret_cast<const f32x16*>(w);
  f32x16 wv[4];
#pragma unroll
  for (int c = 0; c < 4; ++c) wv[c] = w16[c];

  float acc[IPB];
#pragma unroll
  for (int ii = 0; ii < IPB; ++ii) acc[ii] = 0.f;

#pragma unroll
  for (int ii = 0; ii < IPB; ++ii) {
    const f32x16* r16 = reinterpret_cast<const f32x16*>(rows + ii * F_TOT);
#pragma unroll
    for (int c = 0; c < 4; ++c) {                   // 16-float row chunk
      const f32x16 rv = r16[c];                     // s_load_dwordx16
#pragma unroll
      for (int q4 = 0; q4 < 4; ++q4) {              // k ascending
        const float4 hv = hj[c * 4 + q4];
        acc[ii] = fmaf(wv[c][q4 * 4 + 0], fabsf(hv.x - rv[q4 * 4 + 0]), acc[ii]);
        acc[ii] = fmaf(wv[c][q4 * 4 + 1], fabsf(hv.y - rv[q4 * 4 + 1]), acc[ii]);
        acc[ii] = fmaf(wv[c][q4 * 4 + 2], fabsf(hv.z - rv[q4 * 4 + 2]), acc[ii]);
        acc[ii] = fmaf(wv[c][q4 * 4 + 3], fabsf(hv.w - rv[q4 * 4 + 3]), acc[ii]);
      }
    }
  }

  // Epilogue. sigmoid(x)>0.5 <=> x>0; selected = A?y:(1-y) = sigmoid(|x|);
  // log(sigmoid(|x|)+1e-8) = -log(1+exp(-|x|)) + O(2e-8).
  float logsum = 0.f;
  float* Abase = Aout + (size_t)b * GN * GN;
#pragma unroll
  for (int ii = 0; ii < IPB; ++ii) {
    const int i = is + ii;
    const float x = acc[ii];
    const float lt = -__logf(1.f + __expf(-fabsf(x)));
    float Aval = (x > 0.f) ? 1.f : 0.f;
    if (i == j) Aval = 1.f;     // diagonal: forced 1, excluded from log-sum
    else        logsum += lt;
    Abase[(size_t)i * GN + j] = Aval;   // lanes = consecutive j: coalesced
  }

  // Deterministic intra-block reduction (fixed shuffle-tree order).
#pragma unroll
  for (int off = 32; off > 0; off >>= 1)
    logsum += __shfl_down(logsum, off, 64);
  __shared__ float red[2];
  const int lane = threadIdx.x & 63;
  const int wid  = threadIdx.x >> 6;
  if (lane == 0) red[wid] = logsum;
  __syncthreads();
  // Transposed layout: consecutive b in consecutive addresses per q-slice.
  if (threadIdx.x == 0) part[q * GB + b] = red[0] + red[1];
}

// probs[b] = sum of the 32 slice partials, fixed order; each of the 32 loads
// is fully coalesced across the 64 threads (part is [ISPLIT][GB]).
__global__ __launch_bounds__(64) void glcn_reduce(
    const float* __restrict__ part, float* __restrict__ probs) {
  const int b = threadIdx.x;
  float s = 0.f;
#pragma unroll
  for (int q = 0; q < ISPLIT; ++q) s += part[q * GB + b];
  probs[b] = s;
}

extern "C" void kernel_launch(void* const* d_in, const int* in_sizes, int n_in,
                              void* d_out, int out_size, void* d_ws, size_t ws_size,
                              hipStream_t stream) {
  const float* h = (const float*)d_in[0];   // [64,128,80] f32
  const float* w = (const float*)d_in[1];   // [64,1] f32
  float* Aout  = (float*)d_out;                       // [64,128,128]
  float* probs = Aout + (size_t)GB * GN * GN;         // [64]
  float* part  = (float*)d_ws;                        // ISPLIT*GB floats

  glcn_main<<<GB * ISPLIT, 128, 0, stream>>>(h, w, Aout, part);
  glcn_reduce<<<1, 64, 0, stream>>>(part, probs);
}

// Round 16
// 14.344 us; speedup vs baseline: 1.0150x; 1.0150x over previous
//
#include <hip/hip_runtime.h>

#define GB 64
#define GN 128
#define F_OBS 64
#define F_TOT 80
#define NBLK 1024           // 64 batches x 16 block-pairs
#define NT 256              // 4 waves; g = tid>>7 picks the row-quad
#define IPT 4               // rows per thread (unchanged economics)

// R16: structural-tax round. R13 calibration: t_hot ~3us, fixed ~10us ->
// attack dispatch/prologue/epilogue overhead, not the MAC loop (R10/R12/R15
// all showed the loop is at its shape's floor).
//  1. 1024 x 256thr instead of 2048 x 128thr: same waves, same 4 waves/SIMD,
//     half the WG-dispatch events (R9: +2048 WGs cost ~+2.5us at const work).
//  2. part[] written PER-WAVE (shfl tree only): no LDS, no __syncthreads in
//     the main kernel. Reduce sums 64 coalesced slices per batch.
//  3. logsum via one log: sum(-log(1+e^-|x|)) = -log(prod(1+e^-|x|)),
//     factors in [1,2] -> product in [1,16], no overflow; diagonal factor 1.
//     3 fewer quarter-rate v_log per thread.
// Keep: XCD-clustered batches (R14, bijective for 1024: all 16 blocks of a
// batch on blk&7), own-row prefetch once (R10), rows on the scalar pipe
// (R7 lesson), two plain dispatches (R5/R7/R11 lesson).
__global__ __launch_bounds__(NT, 4) void glcn_main(
    const float* __restrict__ h, const float* __restrict__ w,
    float* __restrict__ Aout, float* __restrict__ part) {
  const int blk = blockIdx.x;
  const int b   = (blk & 7) + 8 * ((blk >> 3) & 7);  // batch: XCD-clustered
  const int qq  = blk >> 6;                          // 0..15 block-pair index
  const int tid = threadIdx.x;
  const int j   = tid & (GN - 1);
  const int g   = __builtin_amdgcn_readfirstlane(tid >> 7);  // 0..1
  const int is  = qq * 8 + g * IPT;                  // wave-uniform row base

  const float* rowj = h + ((size_t)(b * GN + j)) * F_TOT;    // per-lane
  const float* rows = h + ((size_t)(b * GN + is)) * F_TOT;   // uniform->s_load

  // Own row prefetched once: 16 independent float4 loads, one drain.
  float4 hj[F_OBS / 4];
#pragma unroll
  for (int kq = 0; kq < F_OBS / 4; ++kq)
    hj[kq] = *reinterpret_cast<const float4*>(rowj + 4 * kq);

  float acc[IPT];
#pragma unroll
  for (int ii = 0; ii < IPT; ++ii) acc[ii] = 0.f;

#pragma unroll
  for (int kq = 0; kq < F_OBS / 4; ++kq) {
    const float4 hv = hj[kq];
    const float4 wv = *reinterpret_cast<const float4*>(w + 4 * kq);  // scalar
#pragma unroll
    for (int ii = 0; ii < IPT; ++ii) {
      const float* ri = rows + ii * F_TOT + 4 * kq;   // scalar dwordx4
      acc[ii] = fmaf(wv.x, fabsf(hv.x - ri[0]), acc[ii]);
      acc[ii] = fmaf(wv.y, fabsf(hv.y - ri[1]), acc[ii]);
      acc[ii] = fmaf(wv.z, fabsf(hv.z - ri[2]), acc[ii]);
      acc[ii] = fmaf(wv.w, fabsf(hv.w - ri[3]), acc[ii]);
    }
  }

  // Epilogue. A[i][j] = (x>0)|(i==j); selected = sigmoid(|x|);
  // per-thread loglik = -log( prod_i (i==j ? 1 : 1+exp(-|x_i|)) ).
  float prod = 1.f;
  float* Abase = Aout + (size_t)b * GN * GN;
#pragma unroll
  for (int ii = 0; ii < IPT; ++ii) {
    const int i = is + ii;
    const float x = acc[ii];
    const float f = 1.f + __expf(-fabsf(x));
    float Aval = (x > 0.f) ? 1.f : 0.f;
    if (i == j) Aval = 1.f;      // diagonal: forced 1, excluded from loglik
    else        prod *= f;
    Abase[(size_t)i * GN + j] = Aval;   // lanes = consecutive j: coalesced
  }
  float lsum = -__logf(prod);

  // Per-WAVE reduction only: shfl tree, lane 0 stores. No LDS, no barrier.
#pragma unroll
  for (int off = 32; off > 0; off >>= 1)
    lsum += __shfl_down(lsum, off, 64);
  const int wid = tid >> 6;                     // 0..3
  if ((tid & 63) == 0) {
    const int slice = qq * 4 + wid;             // 0..63, unique per (blk,wave)
    part[(size_t)slice * GB + b] = lsum;        // [64][GB]: coalesced reduce
  }
}

// probs[b] = sum of the 64 wave partials, fixed slice order (deterministic);
// every load is fully coalesced across the 64 threads.
__global__ __launch_bounds__(64) void glcn_reduce(
    const float* __restrict__ part, float* __restrict__ probs) {
  const int b = threadIdx.x;
  float s = 0.f;
#pragma unroll
  for (int q = 0; q < 64; ++q) s += part[(size_t)q * GB + b];
  probs[b] = s;
}

extern "C" void kernel_launch(void* const* d_in, const int* in_sizes, int n_in,
                              void* d_out, int out_size, void* d_ws, size_t ws_size,
                              hipStream_t stream) {
  const float* h = (const float*)d_in[0];   // [64,128,80] f32
  const float* w = (const float*)d_in[1];   // [64,1] f32
  float* Aout  = (float*)d_out;                       // [64,128,128]
  float* probs = Aout + (size_t)GB * GN * GN;         // [64]
  float* part  = (float*)d_ws;                        // 64*GB floats (16KB)

  glcn_main<<<NBLK, NT, 0, stream>>>(h, w, Aout, part);
  glcn_reduce<<<1, 64, 0, stream>>>(part, probs);
}